// Round 2
// baseline (116.253 us; speedup 1.0000x reference)
//
#include <hip/hip_runtime.h>
#include <hip/hip_bf16.h>

// Chamfer, B=4, N=M=8192 fp32 -> scalar. Round 2: remove LDS from the inner loop.
// prep: pack both point sets as float4(-2x,-2y,-2z,x^2+y^2+z^2) into ws (512 KB) + init mins.
// main: P-side 8 pts/thread in regs (un-scaled by -0.5); Q-side read broadcast (block-uniform
// index -> scalar/L1 loads) from the packed array; 3 FMA + 0.5 min3 per pair = 3.5 VALU/pair.
// Register ping-pong (4+4 q points) hides load latency. Mins combined via uint atomicMin.

#define BATCH 4
#define NPTS 8192
#define MS 16               // m-chunks per direction
#define RPT 8               // query points per thread
#define CHUNK (NPTS / MS)   // 512 q-points per block
#define SETPTS (BATCH * NPTS)  // 32768

__global__ __launch_bounds__(256) void chamfer_prep_kernel(
    const float* __restrict__ p1, const float* __restrict__ p2,
    float4* __restrict__ pre, unsigned int* __restrict__ wmin, float* __restrict__ out) {
  const int i = blockIdx.x * 256 + threadIdx.x;  // 0..65535 ; block never straddles sets
  const float* src = (i < SETPTS) ? (p1 + 3 * (size_t)i) : (p2 + 3 * (size_t)(i - SETPTS));
  const float x = src[0], y = src[1], z = src[2];
  pre[i] = make_float4(-2.f * x, -2.f * y, -2.f * z, fmaf(x, x, fmaf(y, y, z * z)));
  wmin[i] = 0x7F800000u;  // +inf
  if (i == 0) out[0] = 0.f;
}

__global__ __launch_bounds__(256) void chamfer_min_kernel(
    const float4* __restrict__ pre, unsigned int* __restrict__ wmin) {
  const int mchunk = blockIdx.x;  // 0..MS-1
  const int nblk = blockIdx.y;    // 0..NPTS/(RPT*256)-1
  const int zb = blockIdx.z;      // 0..2*BATCH-1
  const int dir = zb >> 2;        // 0: P=p1,Q=p2 ; 1: P=p2,Q=p1
  const int b = zb & 3;
  const float4* __restrict__ Pp = pre + (dir ? SETPTS : 0) + (size_t)b * NPTS;
  const float4* __restrict__ Qp = pre + (dir ? 0 : SETPTS) + (size_t)b * NPTS;
  unsigned int* __restrict__ wm = wmin + ((size_t)dir * BATCH + b) * NPTS;

  const int t = threadIdx.x;

  float px[RPT], py[RPT], pz[RPT], pw[RPT], acc[RPT];
#pragma unroll
  for (int r = 0; r < RPT; ++r) {
    const int n = nblk * (RPT * 256) + r * 256 + t;
    const float4 v = Pp[n];           // coalesced 16B
    px[r] = -0.5f * v.x;              // recover raw coords from premultiplied form
    py[r] = -0.5f * v.y;
    pz[r] = -0.5f * v.z;
    pw[r] = v.w;                      // |p|^2 for the epilogue
    acc[r] = INFINITY;                // tracks min over q of (|q|^2 - 2 p.q)
  }

  const float4* __restrict__ Qc = Qp + mchunk * CHUNK;  // block-uniform base

  // register ping-pong: compute on one group of 4 q while the other group loads
  float4 qa0 = Qc[0], qa1 = Qc[1], qa2 = Qc[2], qa3 = Qc[3];

  for (int m = 0; m < CHUNK; m += 8) {
    const int mb = (m + 4) & (CHUNK - 1);   // wraps harmlessly on last iter
    float4 qb0 = Qc[mb], qb1 = Qc[mb + 1], qb2 = Qc[mb + 2], qb3 = Qc[mb + 3];
#pragma unroll
    for (int r = 0; r < RPT; ++r) {
      const float c0 = fmaf(px[r], qa0.x, fmaf(py[r], qa0.y, fmaf(pz[r], qa0.z, qa0.w)));
      const float c1 = fmaf(px[r], qa1.x, fmaf(py[r], qa1.y, fmaf(pz[r], qa1.z, qa1.w)));
      const float c2 = fmaf(px[r], qa2.x, fmaf(py[r], qa2.y, fmaf(pz[r], qa2.z, qa2.w)));
      const float c3 = fmaf(px[r], qa3.x, fmaf(py[r], qa3.y, fmaf(pz[r], qa3.z, qa3.w)));
      acc[r] = fminf(fminf(acc[r], c0), c1);  // v_min3
      acc[r] = fminf(fminf(acc[r], c2), c3);  // v_min3
    }
    const int ma = (m + 8) & (CHUNK - 1);
    qa0 = Qc[ma]; qa1 = Qc[ma + 1]; qa2 = Qc[ma + 2]; qa3 = Qc[ma + 3];
#pragma unroll
    for (int r = 0; r < RPT; ++r) {
      const float c0 = fmaf(px[r], qb0.x, fmaf(py[r], qb0.y, fmaf(pz[r], qb0.z, qb0.w)));
      const float c1 = fmaf(px[r], qb1.x, fmaf(py[r], qb1.y, fmaf(pz[r], qb1.z, qb1.w)));
      const float c2 = fmaf(px[r], qb2.x, fmaf(py[r], qb2.y, fmaf(pz[r], qb2.z, qb2.w)));
      const float c3 = fmaf(px[r], qb3.x, fmaf(py[r], qb3.y, fmaf(pz[r], qb3.z, qb3.w)));
      acc[r] = fminf(fminf(acc[r], c0), c1);
      acc[r] = fminf(fminf(acc[r], c2), c3);
    }
  }

#pragma unroll
  for (int r = 0; r < RPT; ++r) {
    const int n = nblk * (RPT * 256) + r * 256 + t;
    const float v = fmaxf(acc[r] + pw[r], 0.f);  // clamp keeps uint-ordered atomicMin valid
    atomicMin(&wm[n], __float_as_uint(v));
  }
}

__global__ __launch_bounds__(256) void chamfer_reduce_kernel(const unsigned int* __restrict__ wmin,
                                                             float* __restrict__ out) {
  // 2*BATCH*NPTS = 65536 elements; 64 blocks x 256 threads x 4 elems
  float s = 0.f;
  const int base = blockIdx.x * 1024 + threadIdx.x;
#pragma unroll
  for (int k = 0; k < 4; ++k) s += __uint_as_float(wmin[base + k * 256]);
#pragma unroll
  for (int off = 32; off > 0; off >>= 1) s += __shfl_down(s, off, 64);
  __shared__ float wsum[4];
  const int lane = threadIdx.x & 63, wid = threadIdx.x >> 6;
  if (lane == 0) wsum[wid] = s;
  __syncthreads();
  if (threadIdx.x == 0) atomicAdd(out, wsum[0] + wsum[1] + wsum[2] + wsum[3]);
}

extern "C" void kernel_launch(void* const* d_in, const int* in_sizes, int n_in,
                              void* d_out, int out_size, void* d_ws, size_t ws_size,
                              hipStream_t stream) {
  const float* p1 = (const float*)d_in[0];
  const float* p2 = (const float*)d_in[1];
  float* out = (float*)d_out;
  unsigned int* wmin = (unsigned int*)d_ws;                     // 65536 u32 = 256 KB
  float4* pre = (float4*)((char*)d_ws + 2 * SETPTS * sizeof(unsigned int));  // 512 KB

  chamfer_prep_kernel<<<dim3(2 * SETPTS / 256), dim3(256), 0, stream>>>(p1, p2, pre, wmin, out);

  dim3 grid(MS, NPTS / (RPT * 256), 2 * BATCH);
  chamfer_min_kernel<<<grid, dim3(256), 0, stream>>>(pre, wmin);

  chamfer_reduce_kernel<<<dim3(64), dim3(256), 0, stream>>>(wmin, out);
}

// Round 3
// 97.646 us; speedup vs baseline: 1.1906x; 1.1906x over previous
//
#include <hip/hip_runtime.h>
#include <hip/hip_bf16.h>

// Chamfer, B=4, N=M=8192 fp32 -> scalar. Round 3: premultiplied Q (3.5 VALU/pair)
// + LDS broadcast for Q (short latency, conflict-free) + 1024 blocks (16 waves/CU).
// Round-2 lesson: uniform global loads in the K-loop stall at 8 waves/CU; LDS broadcast
// at 16 waves/CU kept VALU at 111% in round 1.

#define BATCH 4
#define NPTS 8192
#define MS 32                  // m-chunks per direction
#define RPT 8                  // n-points per thread
#define CHUNK (NPTS / MS)      // 256 q-points per block
#define SETPTS (BATCH * NPTS)  // 32768

__global__ __launch_bounds__(256) void chamfer_prep_kernel(
    const float* __restrict__ p1, const float* __restrict__ p2,
    float4* __restrict__ pre, unsigned int* __restrict__ wmin, float* __restrict__ out) {
  const int i = blockIdx.x * 256 + threadIdx.x;  // 0..65535; blocks never straddle sets
  const float* src = (i < SETPTS) ? (p1 + 3 * (size_t)i) : (p2 + 3 * (size_t)(i - SETPTS));
  const float x = src[0], y = src[1], z = src[2];
  pre[i] = make_float4(-2.f * x, -2.f * y, -2.f * z, fmaf(x, x, fmaf(y, y, z * z)));
  wmin[i] = 0x7F800000u;  // +inf
  if (i == 0) out[0] = 0.f;
}

__global__ __launch_bounds__(256) void chamfer_min_kernel(
    const float4* __restrict__ pre, unsigned int* __restrict__ wmin) {
  const int mchunk = blockIdx.x;  // 0..MS-1
  const int nblk = blockIdx.y;    // 0..3
  const int zb = blockIdx.z;      // 0..7
  const int dir = zb >> 2;        // 0: P=p1,Q=p2 ; 1: P=p2,Q=p1
  const int b = zb & 3;
  const float4* __restrict__ Pp = pre + (dir ? SETPTS : 0) + (size_t)b * NPTS;
  const float4* __restrict__ Qp = pre + (dir ? 0 : SETPTS) + (size_t)b * NPTS;
  unsigned int* __restrict__ wm = wmin + ((size_t)dir * BATCH + b) * NPTS;

  const int t = threadIdx.x;

  // stage this block's 256 premultiplied q points into LDS (once)
  __shared__ float4 sQ[CHUNK];
  sQ[t] = Qp[mchunk * CHUNK + t];

  float px[RPT], py[RPT], pz[RPT], pw[RPT], acc[RPT];
#pragma unroll
  for (int r = 0; r < RPT; ++r) {
    const int n = nblk * (RPT * 256) + r * 256 + t;
    const float4 v = Pp[n];  // coalesced 16B
    px[r] = -0.5f * v.x;     // recover raw coords from premultiplied form
    py[r] = -0.5f * v.y;
    pz[r] = -0.5f * v.z;
    pw[r] = v.w;             // |p|^2 for the epilogue
    acc[r] = INFINITY;       // min over q of (|q|^2 - 2 p.q)
  }
  __syncthreads();

  for (int j = 0; j < CHUNK; j += 4) {
    const float4 q0 = sQ[j];      // broadcast ds_read_b128, conflict-free
    const float4 q1 = sQ[j + 1];
    const float4 q2 = sQ[j + 2];
    const float4 q3 = sQ[j + 3];
#pragma unroll
    for (int r = 0; r < RPT; ++r) {
      const float c0 = fmaf(px[r], q0.x, fmaf(py[r], q0.y, fmaf(pz[r], q0.z, q0.w)));
      const float c1 = fmaf(px[r], q1.x, fmaf(py[r], q1.y, fmaf(pz[r], q1.z, q1.w)));
      const float c2 = fmaf(px[r], q2.x, fmaf(py[r], q2.y, fmaf(pz[r], q2.z, q2.w)));
      const float c3 = fmaf(px[r], q3.x, fmaf(py[r], q3.y, fmaf(pz[r], q3.z, q3.w)));
      acc[r] = fminf(fminf(acc[r], c0), c1);  // v_min3_f32
      acc[r] = fminf(fminf(acc[r], c2), c3);  // v_min3_f32
    }
  }

#pragma unroll
  for (int r = 0; r < RPT; ++r) {
    const int n = nblk * (RPT * 256) + r * 256 + t;
    const float v = fmaxf(acc[r] + pw[r], 0.f);  // clamp keeps uint-ordered atomicMin valid
    atomicMin(&wm[n], __float_as_uint(v));
  }
}

__global__ __launch_bounds__(256) void chamfer_reduce_kernel(const unsigned int* __restrict__ wmin,
                                                             float* __restrict__ out) {
  // 65536 elements; 64 blocks x 256 threads x 4 elems
  float s = 0.f;
  const int base = blockIdx.x * 1024 + threadIdx.x;
#pragma unroll
  for (int k = 0; k < 4; ++k) s += __uint_as_float(wmin[base + k * 256]);
#pragma unroll
  for (int off = 32; off > 0; off >>= 1) s += __shfl_down(s, off, 64);
  __shared__ float wsum[4];
  const int lane = threadIdx.x & 63, wid = threadIdx.x >> 6;
  if (lane == 0) wsum[wid] = s;
  __syncthreads();
  if (threadIdx.x == 0) atomicAdd(out, wsum[0] + wsum[1] + wsum[2] + wsum[3]);
}

extern "C" void kernel_launch(void* const* d_in, const int* in_sizes, int n_in,
                              void* d_out, int out_size, void* d_ws, size_t ws_size,
                              hipStream_t stream) {
  const float* p1 = (const float*)d_in[0];
  const float* p2 = (const float*)d_in[1];
  float* out = (float*)d_out;
  unsigned int* wmin = (unsigned int*)d_ws;                                  // 256 KB
  float4* pre = (float4*)((char*)d_ws + 2 * SETPTS * sizeof(unsigned int));  // 1 MB

  chamfer_prep_kernel<<<dim3(2 * SETPTS / 256), dim3(256), 0, stream>>>(p1, p2, pre, wmin, out);

  dim3 grid(MS, NPTS / (RPT * 256), 2 * BATCH);
  chamfer_min_kernel<<<grid, dim3(256), 0, stream>>>(pre, wmin);

  chamfer_reduce_kernel<<<dim3(64), dim3(256), 0, stream>>>(wmin, out);
}